// Round 15
// baseline (691.931 us; speedup 1.0000x reference)
//
#include <hip/hip_runtime.h>
#include <math.h>

// ---------------- model constants ----------------
#define BB 16
#define LL 2048
#define CHUNK 10
#define DD 256
#define NLAYERS 4
#define FFD 1024
#define NCLS 10
#define HSTRC 2056  // float2 stride per channel of Hf (2049 bins + pad)

typedef short bf16x8 __attribute__((ext_vector_type(8)));
typedef short s16x4 __attribute__((ext_vector_type(4)));
typedef float f32x4 __attribute__((ext_vector_type(4)));

__device__ __forceinline__ unsigned short f2bf(float f) {
    unsigned int u = __builtin_bit_cast(unsigned int, f);
    u = (u + 0x7FFF + ((u >> 16) & 1)) >> 16;
    return (unsigned short)u;
}
__device__ __forceinline__ float bf2f(unsigned short s) {
    unsigned int u = ((unsigned int)s) << 16;
    return __builtin_bit_cast(float, u);
}
__device__ __forceinline__ float bfLO(unsigned v) { return __builtin_bit_cast(float, v << 16); }
__device__ __forceinline__ float bfHI(unsigned v) { return __builtin_bit_cast(float, v & 0xFFFF0000u); }

#define PADC(a) ((a) + ((a) >> 4))

__device__ __forceinline__ float2 cmulf(float2 a, float2 b) {
    return make_float2(fmaf(-a.y, b.y, a.x * b.x), fmaf(a.y, b.x, a.x * b.y));
}

#define GLL16(gsrc, ldst) \
    __builtin_amdgcn_global_load_lds((const __attribute__((address_space(1))) void*)(gsrc), \
                                     (__attribute__((address_space(3))) void*)(ldst), 16, 0, 0)

// ================= embed: xs(bf16) = reshape(x)@inp_w + inp_b + PE =================
__global__ __launch_bounds__(256)
void embed_k(const float* __restrict__ x, const float* __restrict__ iw,
             const float* __restrict__ ib, unsigned short* __restrict__ xsb)
{
    const int tid = threadIdx.x;
    const size_t row0 = (size_t)blockIdx.x * 8;
    const int i2 = (tid >> 1) * 2;
    const float div = expf(-0.03597789207803197f * (float)i2);
    float wcol[CHUNK];
#pragma unroll
    for (int c = 0; c < CHUNK; ++c) wcol[c] = iw[c * DD + tid];
    const float bv = ib[tid];
    for (int rr = 0; rr < 8; ++rr) {
        size_t row = row0 + rr;
        int l = (int)(row & (LL - 1));
        const float* xr = x + row * CHUNK;
        float acc = bv;
#pragma unroll
        for (int c = 0; c < CHUNK; ++c) acc += xr[c] * wcol[c];
        float sv, cv;
        sincosf((float)l * div, &sv, &cv);
        acc += (tid & 1) ? cv : sv;
        xsb[row * DD + tid] = f2bf(acc);
    }
}

// ================= filter MLP (all layers): hTall[layer][d][l] =================
__global__ __launch_bounds__(256)
void filt_all_k(const float* __restrict__ fw1, const float* __restrict__ fb1,
                const float* __restrict__ fw2, const float* __restrict__ fb2,
                float* __restrict__ hTall)
{
    __shared__ float pe[16];
    __shared__ float hid[64];
    const int tid = threadIdx.x;
    const int layer = blockIdx.x >> 11;
    const int l = blockIdx.x & 2047;
    const float* w1 = fw1 + layer * 1024;
    const float* b1 = fb1 + layer * 64;
    const float* w2 = fw2 + layer * 16384;
    const float* b2 = fb2 + layer * 256;
    if (tid < 16) {
        int i2 = (tid >> 1) * 2;
        float div = expf(-0.5756462732485114f * (float)i2);
        float sv, cv;
        sincosf((float)l * div, &sv, &cv);
        pe[tid] = (tid & 1) ? cv : sv;
    }
    __syncthreads();
    if (tid < 64) {
        float a = b1[tid];
#pragma unroll
        for (int e = 0; e < 16; ++e) a += pe[e] * w1[e * 64 + tid];
        hid[tid] = 0.5f * a * (1.0f + erff(a * 0.70710678118f));
    }
    __syncthreads();
    float a = b2[tid];
#pragma unroll
    for (int h = 0; h < 64; ++h) a += hid[h] * w2[h * DD + tid];
    hTall[(size_t)layer * 524288 + (size_t)tid * LL + l] = a;
}

// ====== in-place radix-8 Stockham FFT, N=2048 = 8*8*8*4, single float2 buffer ======
__device__ __forceinline__ void dft4c(float2 a, float2 b, float2 c, float2 d,
                                      float2& F0, float2& F1, float2& F2, float2& F3)
{
    float t0r = a.x + c.x, t0i = a.y + c.y;
    float t1r = a.x - c.x, t1i = a.y - c.y;
    float t2r = b.x + d.x, t2i = b.y + d.y;
    float t3r = b.x - d.x, t3i = b.y - d.y;
    F0 = make_float2(t0r + t2r, t0i + t2i);
    F2 = make_float2(t0r - t2r, t0i - t2i);
    F1 = make_float2(t1r + t3i, t1i - t3r);   // t1 - i*t3
    F3 = make_float2(t1r - t3i, t1i + t3r);   // t1 + i*t3
}

template <int SH>
__device__ __forceinline__ void stage8ip(float2* __restrict__ A, int tid)
{
    constexpr int ST = 1 << SH;
    const int p = tid >> SH;
    const int q = tid & (ST - 1);
    float2 x0 = A[PADC(tid)];
    float2 x1 = A[PADC(tid + 256)];
    float2 x2 = A[PADC(tid + 512)];
    float2 x3 = A[PADC(tid + 768)];
    float2 x4 = A[PADC(tid + 1024)];
    float2 x5 = A[PADC(tid + 1280)];
    float2 x6 = A[PADC(tid + 1536)];
    float2 x7 = A[PADC(tid + 1792)];
    float2 E0, E1, E2, E3, O0, O1, O2, O3;
    dft4c(x0, x2, x4, x6, E0, E1, E2, E3);
    dft4c(x1, x3, x5, x7, O0, O1, O2, O3);
    const float C8 = 0.70710678118654752f;
    float2 y0 = make_float2(E0.x + O0.x, E0.y + O0.y);
    float2 y4 = make_float2(E0.x - O0.x, E0.y - O0.y);
    float a1 = C8 * (O1.x + O1.y), b1 = C8 * (O1.y - O1.x);       // w8^1 * O1
    float2 y1 = make_float2(E1.x + a1, E1.y + b1);
    float2 y5 = make_float2(E1.x - a1, E1.y - b1);
    float2 y2 = make_float2(E2.x + O2.y, E2.y - O2.x);            // -i * O2
    float2 y6 = make_float2(E2.x - O2.y, E2.y + O2.x);
    float a3 = -C8 * (O3.x - O3.y), b3 = -C8 * (O3.x + O3.y);     // w8^3 * O3
    float2 y3 = make_float2(E3.x + a3, E3.y + b3);
    float2 y7 = make_float2(E3.x - a3, E3.y - b3);
    const int k0 = p << SH;
    float s1, c1;
    __sincosf(-3.0679615757712823e-3f * (float)k0, &s1, &c1);     // -2pi/2048 * k0
    float2 w1 = make_float2(c1, s1);
    float2 w2 = cmulf(w1, w1);
    float2 w3 = cmulf(w2, w1);
    float2 w4 = cmulf(w2, w2);
    float2 w5 = cmulf(w3, w2);
    float2 w6 = cmulf(w3, w3);
    float2 w7 = cmulf(w4, w3);
    float2 o1 = cmulf(w1, y1);
    float2 o2 = cmulf(w2, y2);
    float2 o3 = cmulf(w3, y3);
    float2 o4 = cmulf(w4, y4);
    float2 o5 = cmulf(w5, y5);
    float2 o6 = cmulf(w6, y6);
    float2 o7 = cmulf(w7, y7);
    __syncthreads();
    const int ob = q + ((ST * p) << 3);
    A[PADC(ob)] = y0;
    A[PADC(ob + ST)] = o1;
    A[PADC(ob + 2 * ST)] = o2;
    A[PADC(ob + 3 * ST)] = o3;
    A[PADC(ob + 4 * ST)] = o4;
    A[PADC(ob + 5 * ST)] = o5;
    A[PADC(ob + 6 * ST)] = o6;
    A[PADC(ob + 7 * ST)] = o7;
    __syncthreads();
}

__device__ __forceinline__ void stage4fip(float2* __restrict__ A, int tid)
{
    float2 v[2][4];
#pragma unroll
    for (int jj = 0; jj < 2; ++jj) {
        int u = tid + (jj << 8);
        v[jj][0] = A[PADC(u)];
        v[jj][1] = A[PADC(u + 512)];
        v[jj][2] = A[PADC(u + 1024)];
        v[jj][3] = A[PADC(u + 1536)];
    }
    __syncthreads();
#pragma unroll
    for (int jj = 0; jj < 2; ++jj) {
        int u = tid + (jj << 8);
        float2 F0, F1, F2, F3;
        dft4c(v[jj][0], v[jj][1], v[jj][2], v[jj][3], F0, F1, F2, F3);
        A[PADC(u)] = F0;
        A[PADC(u + 512)] = F1;
        A[PADC(u + 1024)] = F2;
        A[PADC(u + 1536)] = F3;
    }
    __syncthreads();
}

__device__ __forceinline__ void fft2048ip(float2* __restrict__ A, int tid)
{
    stage8ip<0>(A, tid);
    stage8ip<3>(A, tid);
    stage8ip<6>(A, tid);
    stage4fip(A, tid);
}

// ================= Hf (all layers) = rfft_4096(zero-pad(h)) per channel =================
__global__ __launch_bounds__(256)
void ffth_all_k(const float* __restrict__ hTall, float2* __restrict__ Hfall)
{
    __shared__ float2 A2[2176];
    const int tid = threadIdx.x;
    const int layer = blockIdx.x >> 8;
    const int d = blockIdx.x & 255;
    const float2* rowf = reinterpret_cast<const float2*>(hTall + (size_t)layer * 524288 + (size_t)d * LL);
#pragma unroll
    for (int j = 0; j < 4; ++j) {
        int u = tid + (j << 8);
        A2[PADC(u)] = rowf[u];
        A2[PADC(u + 1024)] = make_float2(0.0f, 0.0f);
    }
    __syncthreads();
    fft2048ip(A2, tid);
    float2* hf = Hfall + ((size_t)layer * 256 + d) * HSTRC;
#pragma unroll
    for (int j = 0; j < 4; ++j) {
        int k = 1 + tid + (j << 8);
        int m = 2048 - k;
        float2 zk = A2[PADC(k)], zm = A2[PADC(m)];
        float Er = 0.5f * (zk.x + zm.x), Ei = 0.5f * (zk.y - zm.y);
        float Or = 0.5f * (zk.y + zm.y), Oi = -0.5f * (zk.x - zm.x);
        float ts, tc;
        __sincosf(-1.5339807878856412e-3f * (float)k, &ts, &tc);
        float TOr = tc * Or - ts * Oi, TOi = tc * Oi + ts * Or;
        hf[k] = make_float2(Er + TOr, Ei + TOi);
        hf[m] = make_float2(Er - TOr, -(Ei - TOi));
    }
    if (tid == 0) {
        float2 z0 = A2[PADC(0)];
        hf[0] = make_float2(z0.x + z0.y, z0.x - z0.y);
    }
}

// ====== fused conv3 + fft conv (single-buffer in-place): x0T(bf16) -> yT(bf16) ======
__global__ __launch_bounds__(256, 4)
void fftconv_k(const unsigned short* __restrict__ x0T, unsigned short* __restrict__ yT,
               const float2* __restrict__ Hf, const float* __restrict__ sw,
               const float* __restrict__ sb)
{
    __shared__ float2 A2[2176];
    const int tid = threadIdx.x;
    // XCD-locality swizzle: XCD c handles channels d in [32c, 32c+32), all b
    const int w = blockIdx.x;
    const int c = w & 7, s = w >> 3;
    const int d = c * 32 + (s & 31);
    const int b = s >> 5;
    const int blk = b * 256 + d;
    const float w0 = sw[d * 3], w1 = sw[d * 3 + 1], w2 = sw[d * 3 + 2];
    const float bv = sb[d];

    // ---- load bf16 row (field-swap permuted within 64-blocks) into LDS floats ----
    float* rawF = reinterpret_cast<float*>(A2);
    {
        const uint4* rowv = reinterpret_cast<const uint4*>(x0T + (size_t)blk * LL);
        uint4 ld = rowv[tid];
        int p = tid << 3;
        int lB = p & ~63;
        int p6 = p & 63;
        int fg = p6 >> 4;
        int m0 = (p6 >> 2) & 3;
        float4* d0 = reinterpret_cast<float4*>(rawF + lB + m0 * 16 + fg * 4);
        float4* d1 = reinterpret_cast<float4*>(rawF + lB + (m0 + 1) * 16 + fg * 4);
        *d0 = make_float4(bfLO(ld.x), bfHI(ld.x), bfLO(ld.y), bfHI(ld.y));
        *d1 = make_float4(bfLO(ld.z), bfHI(ld.z), bfLO(ld.w), bfHI(ld.w));
    }
    __syncthreads();
    // ---- depthwise conv3 + complex pack into regs ----
    float2 zv[4];
#pragma unroll
    for (int j = 0; j < 4; ++j) {
        int u = tid + (j << 8);
        float xm1 = (u == 0) ? 0.0f : rawF[2 * u - 1];
        float xc0 = rawF[2 * u];
        float xp1 = rawF[2 * u + 1];
        float xp2 = (u == 1023) ? 0.0f : rawF[2 * u + 2];
        zv[j].x = bv + w0 * xm1 + w1 * xc0 + w2 * xp1;
        zv[j].y = bv + w0 * xc0 + w1 * xp1 + w2 * xp2;
    }
    __syncthreads();
#pragma unroll
    for (int j = 0; j < 4; ++j) {
        int u = tid + (j << 8);
        A2[PADC(u)] = zv[j];
        A2[PADC(u + 1024)] = make_float2(0.0f, 0.0f);
    }
    __syncthreads();
    fft2048ip(A2, tid);
    // ---- untangle, multiply by H, retangle ----
    const float2* hf = Hf + (size_t)d * HSTRC;
#pragma unroll
    for (int j = 0; j < 4; ++j) {
        int k = 1 + tid + (j << 8);
        int m = 2048 - k;
        float2 zk = A2[PADC(k)], zm = A2[PADC(m)];
        float Er = 0.5f * (zk.x + zm.x), Ei = 0.5f * (zk.y - zm.y);
        float Or = 0.5f * (zk.y + zm.y), Oi = -0.5f * (zk.x - zm.x);
        float ts, tc;
        __sincosf(-1.5339807878856412e-3f * (float)k, &ts, &tc);
        float TOr = tc * Or - ts * Oi, TOi = tc * Oi + ts * Or;
        float Xpr = Er + TOr, Xpi = Ei + TOi;
        float Xmr = Er - TOr, Xmi = Ei - TOi;
        float2 hk = hf[k], hm = hf[m];
        float Ykr = Xpr * hk.x - Xpi * hk.y, Yki = Xpr * hk.y + Xpi * hk.x;
        float Cr = Xmr * hm.x + Xmi * hm.y, Ci = Xmi * hm.x - Xmr * hm.y;
        float Pr = 0.5f * (Ykr + Cr), Pi = 0.5f * (Yki + Ci);
        float Gr = 0.5f * (Ykr - Cr), Gi = 0.5f * (Yki - Ci);
        float Qr = tc * Gr + ts * Gi, Qi = tc * Gi - ts * Gr;
        A2[PADC(k)] = make_float2(Pr - Qi, -(Pi + Qr));
        A2[PADC(m)] = make_float2(Pr + Qi, Pi - Qr);
    }
    if (tid == 0) {
        float2 z0 = A2[PADC(0)];
        float2 h0 = hf[0];
        float X0 = z0.x + z0.y, X2 = z0.x - z0.y;
        float Y0 = X0 * h0.x, Y2 = X2 * h0.y;
        float P = 0.5f * (Y0 + Y2), Q = 0.5f * (Y0 - Y2);
        A2[PADC(0)] = make_float2(P, -Q);
    }
    __syncthreads();
    fft2048ip(A2, tid);
    const float sc = 1.0f / 2048.0f;
    unsigned* yrow = reinterpret_cast<unsigned*>(yT + (size_t)blk * LL);
#pragma unroll
    for (int j = 0; j < 4; ++j) {
        int u = tid + (j << 8);
        float2 v = A2[PADC(u)];
        float e = v.x * sc, o = -v.y * sc;
        yrow[u] = (unsigned)f2bf(e) | ((unsigned)f2bf(o) << 16);
    }
}

// ================= gate + transpose: yg(B,L,D) bf16 = yT * xp (xp = x1*x2) =================
__global__ __launch_bounds__(256)
void gate_k(const unsigned short* __restrict__ yTb, const unsigned short* __restrict__ px,
            unsigned short* __restrict__ yg)
{
    __shared__ float t[64][65];
    const int tid = threadIdx.x;
    const int blk = blockIdx.x;
    const int b = blk >> 7;
    const int dt = (blk >> 5) & 3;
    const int lt = blk & 31;
    const int d0 = dt << 6, l0 = lt << 6;
    const int r0 = tid >> 6, c = tid & 63;
    for (int rr = 0; rr < 16; ++rr) {
        int dl = rr * 4 + r0;
        t[dl][c] = bf2f(yTb[(((size_t)(b << 8) + d0 + dl) << 11) + l0 + c]);
    }
    __syncthreads();
    const int lid = tid & 63, lr = tid >> 6;
    for (int k = 0; k < 16; ++k) {
        int ll = k * 4 + lr;
        int l = l0 + ll;
        size_t pb = ((size_t)(b * LL + l)) * 256;
        float v = t[lid][ll];
        float g = bf2f(px[pb + d0 + lid]);
        yg[((size_t)(b * LL + l)) * DD + d0 + lid] = f2bf(v * g);
    }
}

// ================= LN + cast to bf16 (bf16 xs input; only after embed) =================
__global__ __launch_bounds__(256)
void lncast_k(const unsigned short* __restrict__ xsb, const float* __restrict__ g,
              const float* __restrict__ b, unsigned short* __restrict__ o)
{
    const int tid = threadIdx.x, lane = tid & 63, wave = tid >> 6;
    const size_t row = (size_t)blockIdx.x * 4 + wave;
    s16x4 vv = reinterpret_cast<const s16x4*>(xsb + row * DD)[lane];
    float v0 = bf2f((unsigned short)vv[0]), v1 = bf2f((unsigned short)vv[1]);
    float v2 = bf2f((unsigned short)vv[2]), v3 = bf2f((unsigned short)vv[3]);
    float s = v0 + v1 + v2 + v3;
#pragma unroll
    for (int off = 32; off > 0; off >>= 1) s += __shfl_xor(s, off, 64);
    float mean = s * (1.0f / 256.0f);
    float e0 = v0 - mean, e1 = v1 - mean, e2 = v2 - mean, e3 = v3 - mean;
    float q = e0 * e0 + e1 * e1 + e2 * e2 + e3 * e3;
#pragma unroll
    for (int off = 32; off > 0; off >>= 1) q += __shfl_xor(q, off, 64);
    float rstd = rsqrtf(q * (1.0f / 256.0f) + 1e-5f);
    float4 gg = reinterpret_cast<const float4*>(g)[lane];
    float4 bb = reinterpret_cast<const float4*>(b)[lane];
    s16x4 r;
    r[0] = (short)f2bf(e0 * rstd * gg.x + bb.x);
    r[1] = (short)f2bf(e1 * rstd * gg.y + bb.y);
    r[2] = (short)f2bf(e2 * rstd * gg.z + bb.z);
    r[3] = (short)f2bf(e3 * rstd * gg.w + bb.w);
    *reinterpret_cast<s16x4*>(o + row * DD + lane * 4) = r;
}

// ================= weight cast + transpose, ALL matrices in one dispatch =================
__global__ __launch_bounds__(256)
void wcast_all_k(const float* __restrict__ in_proj_w, const float* __restrict__ out_w,
                 const float* __restrict__ ffn_w1, const float* __restrict__ ffn_w2,
                 unsigned short* __restrict__ WTb)
{
    const int bid = blockIdx.x;
    const int layer = bid / 768;
    const int r = bid % 768;
    const float* W; unsigned short* WT; int K, N, nt, kt;
    unsigned short* wt = WTb + (size_t)layer * 786432;
    if (r < 192)      { int i = r;       nt = i % 24; kt = i / 24; K = 256;  N = 768;
                        W = in_proj_w + (size_t)layer * 196608; WT = wt; }
    else if (r < 256) { int i = r - 192; nt = i % 8;  kt = i / 8;  K = 256;  N = 256;
                        W = out_w + (size_t)layer * 65536;      WT = wt + 196608; }
    else if (r < 512) { int i = r - 256; nt = i % 32; kt = i / 32; K = 256;  N = 1024;
                        W = ffn_w1 + (size_t)layer * 262144;    WT = wt + 262144; }
    else              { int i = r - 512; nt = i % 8;  kt = i / 8;  K = 1024; N = 256;
                        W = ffn_w2 + (size_t)layer * 262144;    WT = wt + 524288; }
    __shared__ float t[32][33];
    const int tx = threadIdx.x & 31, ty = threadIdx.x >> 5;
    const int n0 = nt * 32, k0 = kt * 32;
#pragma unroll
    for (int j = 0; j < 4; ++j)
        t[ty + 8 * j][tx] = W[(size_t)(k0 + ty + 8 * j) * N + n0 + tx];
    __syncthreads();
#pragma unroll
    for (int j = 0; j < 4; ++j)
        WT[(size_t)(n0 + ty + 8 * j) * K + k0 + tx] = f2bf(t[tx][ty + 8 * j]);
}

// ================= bf16 MFMA GEMM (generic) =================
// MODE 1: GELU -> bf16. MODE 2: += into bf16 out (RMW).
// MODE 3 (in_proj): tiles 0-1 -> x0 transposed(field-swap); tiles 2-5 -> pair tiles
//   computing x1 (cols 0-63 of C) and x2 (cols 64-127), storing xp = x1*x2 (stride 256).
template <int K, int N, int MODE>
__global__ __launch_bounds__(256)
void gemm_k(const unsigned short* __restrict__ A, const unsigned short* __restrict__ WT,
            const float* __restrict__ bias, void* __restrict__ outp, void* __restrict__ outp2)
{
    constexpr int C = N / 128;
    __shared__ unsigned short ldsA[8192];
    __shared__ unsigned short ldsB[8192];
    const int tid = threadIdx.x;
    const int lane = tid & 63, wid = tid >> 6;
    const int nwg = gridDim.x;
    const int w = blockIdx.x;
    const int logical = (w & 7) * (nwg >> 3) + (w >> 3);
    const int row0 = (logical / C) * 128;
    const int col0 = (logical % C) * 128;
    const int wm = (wid >> 1) * 64, wn = (wid & 1) * 64;
    const int fr = lane & 15, fg = lane >> 4;

    f32x4 acc[4][4];
#pragma unroll
    for (int n = 0; n < 4; ++n) {
        int bcol;
        if constexpr (MODE == 3) {
            if (col0 >= 256) {
                int j64 = (col0 - 256) >> 1;
                bcol = (wn == 0 ? 256 : 512) + j64 + n * 16 + fr;
            } else {
                bcol = col0 + wn + n * 16 + fr;
            }
        } else {
            bcol = col0 + wn + n * 16 + fr;
        }
        float bv = bias[bcol];
#pragma unroll
        for (int m = 0; m < 4; ++m) {
            acc[m][n][0] = bv; acc[m][n][1] = bv; acc[m][n][2] = bv; acc[m][n][3] = bv;
        }
    }

    const int srow = wid * 8 + (lane >> 3);
    const int sc = lane & 7;

    for (int kt = 0; kt < K / 64; ++kt) {
        const int k0 = kt * 64;
#pragma unroll
        for (int it = 0; it < 4; ++it) {
            int row = it * 32 + srow;
            int cs = sc ^ (row & 7);
            const char* ga = (const char*)(A + (size_t)(row0 + row) * K + k0) + cs * 16;
            const unsigned short* bsrc;
            if constexpr (MODE == 3) {
                if (col0 >= 256) {
                    int j64 = (col0 - 256) >> 1;
                    int brow = 256 + ((it >> 1) << 8) + j64 + ((it & 1) << 5) + srow;
                    bsrc = WT + (size_t)brow * K + k0;
                } else {
                    bsrc = WT + (size_t)(col0 + row) * K + k0;
                }
            } else {
                bsrc = WT + (size_t)(col0 + row) * K + k0;
            }
            GLL16(ga, (char*)ldsA + it * 4096 + wid * 1024);
            GLL16((const char*)bsrc + cs * 16, (char*)ldsB + it * 4096 + wid * 1024);
        }
        __syncthreads();
#pragma unroll
        for (int ks = 0; ks < 2; ++ks) {
            bf16x8 af[4], bf[4];
#pragma unroll
            for (int m = 0; m < 4; ++m) {
                int ar = wm + m * 16 + fr;
                int slot = (ks * 4 + fg) ^ (ar & 7);
                af[m] = *reinterpret_cast<const bf16x8*>(ldsA + ar * 64 + slot * 8);
            }
#pragma unroll
            for (int n = 0; n < 4; ++n) {
                int br = wn + n * 16 + fr;
                int slot = (ks * 4 + fg) ^ (br & 7);
                bf[n] = *reinterpret_cast<const bf16x8*>(ldsB + br * 64 + slot * 8);
            }
#pragma unroll
            for (int m = 0; m < 4; ++m)
#pragma unroll
                for (int n = 0; n < 4; ++n)
                    acc[m][n] = __builtin_amdgcn_mfma_f32_16x16x32_bf16(af[m], bf[n], acc[m][n], 0, 0, 0);
        }
        __syncthreads();
    }

    if constexpr (MODE == 3) {
        if (col0 < 256) {
            const int b = row0 >> 11;
            const int lb0 = (row0 & (LL - 1)) + wm;
#pragma unroll
            for (int n = 0; n < 4; ++n) {
                int dcol = col0 + wn + n * 16 + fr;
                unsigned short* dst = (unsigned short*)outp +
                    (((size_t)(b << 8) + dcol) << 11) + lb0 + fg * 16;
                unsigned pk[8];
#pragma unroll
                for (int q = 0; q < 8; ++q) {
                    int m = q >> 1, r0 = (q & 1) * 2;
                    pk[q] = (unsigned)f2bf(acc[m][n][r0]) | ((unsigned)f2bf(acc[m][n][r0 + 1]) << 16);
                }
                *reinterpret_cast<uint4*>(dst)     = make_uint4(pk[0], pk[1], pk[2], pk[3]);
                *reinterpret_cast<uint4*>(dst + 8) = make_uint4(pk[4], pk[5], pk[6], pk[7]);
            }
        } else {
            // pair tile: cols 0-63 = x1, cols 64-127 = x2; store xp = x1*x2 (stride 256)
            unsigned short* exch = ldsB;          // dead after K loop; 128x64 shorts = 16KB
            if (wn == 64) {
#pragma unroll
                for (int m = 0; m < 4; ++m)
#pragma unroll
                    for (int n = 0; n < 4; ++n)
#pragma unroll
                        for (int r = 0; r < 4; ++r) {
                            int row = wm + m * 16 + fg * 4 + r;
                            int ccol = n * 16 + fr;
                            exch[row * 64 + ccol] = f2bf(acc[m][n][r]);
                        }
            }
            __syncthreads();
            if (wn == 0) {
                unsigned short* px = (unsigned short*)outp2;
                const int j64 = (col0 - 256) >> 1;
#pragma unroll
                for (int m = 0; m < 4; ++m)
#pragma unroll
                    for (int n = 0; n < 4; ++n)
#pragma unroll
                        for (int r = 0; r < 4; ++r) {
                            int row = wm + m * 16 + fg * 4 + r;
                            int ccol = n * 16 + fr;
                            float xp = acc[m][n][r] * bf2f(exch[row * 64 + ccol]);
                            px[(size_t)(row0 + row) * 256 + j64 + ccol] = f2bf(xp);
                        }
            }
        }
        return;
    }

#pragma unroll
    for (int m = 0; m < 4; ++m) {
        int gr = row0 + wm + m * 16 + fg * 4;
#pragma unroll
        for (int n = 0; n < 4; ++n) {
            int gc = col0 + wn + n * 16 + fr;
#pragma unroll
            for (int r = 0; r < 4; ++r) {
                float v = acc[m][n][r];
                if constexpr (MODE == 1) v = 0.5f * v * (1.0f + erff(v * 0.70710678118f));
                if constexpr (MODE <= 1) {
                    ((unsigned short*)outp)[(size_t)(gr + r) * N + gc] = f2bf(v);
                } else {
                    unsigned short* o = (unsigned short*)outp + (size_t)(gr + r) * N + gc;
                    *o = f2bf(bf2f(*o) + v);
                }
            }
        }
    }
}

// ====== fused GEMM(N=256) + residual(bf16) + LayerNorm + bf16 cast ======
template <int K>
__global__ __launch_bounds__(256)
void gemm_ln_k(const unsigned short* __restrict__ A, const unsigned short* __restrict__ WT,
               const float* __restrict__ bias, const float* __restrict__ lng,
               const float* __restrict__ lnb, unsigned short* __restrict__ xsb,
               unsigned short* __restrict__ xln)
{
    __shared__ unsigned short ldsA[64 * 64];
    __shared__ unsigned short ldsB[256 * 64];
    const int tid = threadIdx.x;
    const int lane = tid & 63, wid = tid >> 6;
    const int nwg = gridDim.x;
    const int w = blockIdx.x;
    const int logical = (w & 7) * (nwg >> 3) + (w >> 3);
    const size_t row0 = (size_t)logical * 64;
    const int fr = lane & 15, fg = lane >> 4;

    f32x4 acc[16];
#pragma unroll
    for (int n = 0; n < 16; ++n) {
        float bv = bias[n * 16 + fr];
        acc[n][0] = bv; acc[n][1] = bv; acc[n][2] = bv; acc[n][3] = bv;
    }

    for (int kt = 0; kt < K / 64; ++kt) {
        const int k0 = kt * 64;
#pragma unroll
        for (int p = 0; p < 2; ++p) {
            int cch = p * 256 + tid;
            int row = cch >> 3;
            int cs = (cch & 7) ^ (row & 7);
            const char* ga = (const char*)(A + (row0 + row) * K + k0) + cs * 16;
            GLL16(ga, (char*)ldsA + p * 4096 + wid * 1024);
        }
#pragma unroll
        for (int p = 0; p < 8; ++p) {
            int cch = p * 256 + tid;
            int row = cch >> 3;
            int cs = (cch & 7) ^ (row & 7);
            const char* gb = (const char*)(WT + (size_t)row * K + k0) + cs * 16;
            GLL16(gb, (char*)ldsB + p * 4096 + wid * 1024);
        }
        __syncthreads();
#pragma unroll
        for (int ks = 0; ks < 2; ++ks) {
            int ar = wid * 16 + fr;
            int slotA = (ks * 4 + fg) ^ (ar & 7);
            bf16x8 af = *reinterpret_cast<const bf16x8*>(ldsA + ar * 64 + slotA * 8);
#pragma unroll
            for (int n = 0; n < 16; ++n) {
                int br = n * 16 + fr;
                int slotB = (ks * 4 + fg) ^ (br & 7);
                bf16x8 bf = *reinterpret_cast<const bf16x8*>(ldsB + br * 64 + slotB * 8);
                acc[n] = __builtin_amdgcn_mfma_f32_16x16x32_bf16(af, bf, acc[n], 0, 0, 0);
            }
        }
        __syncthreads();
    }

    const size_t rbase = row0 + wid * 16 + fg * 4;
#pragma unroll
    for (int r = 0; r < 4; ++r) {
        const unsigned short* xr = xsb + (rbase + r) * DD;
#pragma unroll
        for (int n = 0; n < 16; ++n)
            acc[n][r] += bf2f(xr[fr + 16 * n]);
    }
    float sm[4], sq[4];
#pragma unroll
    for (int r = 0; r < 4; ++r) {
        float s = 0.0f, q = 0.0f;
#pragma unroll
        for (int n = 0; n < 16; ++n) {
            float v = acc[n][r];
            s += v; q += v * v;
        }
#pragma unroll
        for (int off = 1; off < 16; off <<= 1) {
            s += __shfl_xor(s, off, 64);
            q += __shfl_xor(q, off, 64);
        }
        sm[r] = s * (1.0f / 256.0f);
        float var = q * (1.0f / 256.0f) - sm[r] * sm[r];
        sq[r] = rsqrtf(var + 1e-5f);
    }
    float gv[16], bvv[16];
#pragma unroll
    for (int n = 0; n < 16; ++n) {
        gv[n] = lng[fr + 16 * n];
        bvv[n] = lnb[fr + 16 * n];
    }
#pragma unroll
    for (int r = 0; r < 4; ++r) {
        unsigned short* xw = xsb + (rbase + r) * DD;
        unsigned short* lw = xln + (rbase + r) * DD;
#pragma unroll
        for (int n = 0; n < 16; ++n) {
            int gc = fr + 16 * n;
            float v = acc[n][r];
            xw[gc] = f2bf(v);
            lw[gc] = f2bf((v - sm[r]) * sq[r] * gv[n] + bvv[n]);
        }
    }
}

// ================= mean pool (partial), bf16 xs =================
__global__ __launch_bounds__(256)
void pool_k(const unsigned short* __restrict__ xsb, float* __restrict__ part)
{
    const int tid = threadIdx.x;
    const int b = blockIdx.x >> 4, g = blockIdx.x & 15;
    size_t base = ((size_t)b * LL + g * 128) * DD + tid;
    float s = 0.0f;
    for (int l = 0; l < 128; ++l) s += bf2f(xsb[base + (size_t)l * DD]);
    part[(size_t)blockIdx.x * DD + tid] = s;
}

// ================= final =================
__global__ __launch_bounds__(256)
void final_k(const float* __restrict__ part, const float* __restrict__ ng,
             const float* __restrict__ nb, const float* __restrict__ cw,
             const float* __restrict__ cb, float* __restrict__ out)
{
    __shared__ float pl[256];
    __shared__ float red[4], red2[4];
    const int tid = threadIdx.x, b = blockIdx.x;
    float m = 0.0f;
    for (int g = 0; g < 16; ++g) m += part[((size_t)b * 16 + g) * DD + tid];
    m *= (1.0f / (float)LL);
    const int lane = tid & 63, wave = tid >> 6;
    float s = m;
#pragma unroll
    for (int off = 32; off > 0; off >>= 1) s += __shfl_xor(s, off, 64);
    if (lane == 0) red[wave] = s;
    __syncthreads();
    float mean = (red[0] + red[1] + red[2] + red[3]) * (1.0f / 256.0f);
    float dm = m - mean;
    float qv = dm * dm;
#pragma unroll
    for (int off = 32; off > 0; off >>= 1) qv += __shfl_xor(qv, off, 64);
    if (lane == 0) red2[wave] = qv;
    __syncthreads();
    float var = (red2[0] + red2[1] + red2[2] + red2[3]) * (1.0f / 256.0f);
    pl[tid] = dm * rsqrtf(var + 1e-5f) * ng[tid] + nb[tid];
    __syncthreads();
    if (tid < NCLS) {
        float a = cb[tid];
        for (int dd = 0; dd < 256; ++dd) a += pl[dd] * cw[dd * NCLS + tid];
        out[b * NCLS + tid] = a;
    }
}

// ================= launcher =================
extern "C" void kernel_launch(void* const* d_in, const int* in_sizes, int n_in,
                              void* d_out, int out_size, void* d_ws, size_t ws_size,
                              hipStream_t stream)
{
    (void)in_sizes; (void)n_in; (void)out_size; (void)ws_size;
    const float* x        = (const float*)d_in[0];
    const float* inp_w    = (const float*)d_in[1];
    const float* inp_b    = (const float*)d_in[2];
    const float* in_proj_w= (const float*)d_in[3];
    const float* in_proj_b= (const float*)d_in[4];
    const float* short_w  = (const float*)d_in[5];
    const float* short_b  = (const float*)d_in[6];
    const float* filt_w1  = (const float*)d_in[7];
    const float* filt_b1  = (const float*)d_in[8];
    const float* filt_w2  = (const float*)d_in[9];
    const float* filt_b2  = (const float*)d_in[10];
    const float* out_w    = (const float*)d_in[11];
    const float* out_b    = (const float*)d_in[12];
    const float* ln1_g    = (const float*)d_in[13];
    const float* ln1_b    = (const float*)d_in[14];
    const float* ln2_g    = (const float*)d_in[15];
    const float* ln2_b    = (const float*)d_in[16];
    const float* ffn_w1   = (const float*)d_in[17];
    const float* ffn_b1   = (const float*)d_in[18];
    const float* ffn_w2   = (const float*)d_in[19];
    const float* ffn_b2   = (const float*)d_in[20];
    const float* norm_g   = (const float*)d_in[21];
    const float* norm_b   = (const float*)d_in[22];
    const float* cls_w    = (const float*)d_in[23];
    const float* cls_b    = (const float*)d_in[24];

    float* ws = (float*)d_ws;
    unsigned short* xsb  = (unsigned short*)ws;                 // 16MB bf16 residual stream
    unsigned short* xln  = (unsigned short*)(ws + 4194304);     // 16MB bf16
    unsigned short* x0T  = (unsigned short*)(ws + 8388608);     // 16MB bf16 [B][D][L']
    unsigned short* yT   = (unsigned short*)(ws + 12582912);    // 16MB bf16 [B][D][L]
    unsigned short* projx= (unsigned short*)(ws + 16777216);    // 16MB bf16 xp = x1*x2
    unsigned short* ygp  = x0T;                                 // reuse x0T after fftconv
    unsigned short* hid  = x0T;                                 // 64MB span (x0T..projx)
    float* hTall         = ws + 25165824;                       // 4 x 2MB
    float2* Hfall        = (float2*)(ws + 27262976);            // 4 x 256 x 2056 float2
    float* part          = ws + 31473664;
    unsigned short* WTb  = (unsigned short*)(ws + 31539200);    // 4 x 786432 bf16

    // ---- prologue: weights cast, embed, LN1(0), filters+Hf (x-independent) ----
    wcast_all_k<<<3072, 256, 0, stream>>>(in_proj_w, out_w, ffn_w1, ffn_w2, WTb);
    embed_k<<<4096, 256, 0, stream>>>(x, inp_w, inp_b, xsb);
    lncast_k<<<8192, 256, 0, stream>>>(xsb, ln1_g, ln1_b, xln);
    filt_all_k<<<NLAYERS * 2048, 256, 0, stream>>>(filt_w1, filt_b1, filt_w2, filt_b2, hTall);
    ffth_all_k<<<NLAYERS * 256, 256, 0, stream>>>(hTall, Hfall);

    for (int i = 0; i < NLAYERS; ++i) {
        unsigned short* wt = WTb + (size_t)i * 786432;
        float2* Hf = Hfall + (size_t)i * 256 * HSTRC;
        gemm_k<256, 768, 3><<<1536, 256, 0, stream>>>(
            xln, wt, in_proj_b + i * 768, x0T, projx);
        fftconv_k<<<4096, 256, 0, stream>>>(x0T, yT, Hf, short_w + i * 768, short_b + i * 256);
        gate_k<<<2048, 256, 0, stream>>>(yT, projx, ygp);
        // out-proj: xs += ygp @ ow + ob ; xln = LN2(xs)
        gemm_ln_k<256><<<512, 256, 0, stream>>>(
            ygp, wt + 196608, out_b + i * 256, ln2_g + i * 256, ln2_b + i * 256, xsb, xln);
        gemm_k<256, 1024, 1><<<2048, 256, 0, stream>>>(
            xln, wt + 262144, ffn_b1 + i * 1024, hid, nullptr);
        if (i < NLAYERS - 1) {
            gemm_ln_k<1024><<<512, 256, 0, stream>>>(
                hid, wt + 524288, ffn_b2 + i * 256,
                ln1_g + (i + 1) * 256, ln1_b + (i + 1) * 256, xsb, xln);
        } else {
            gemm_k<1024, 256, 2><<<512, 256, 0, stream>>>(
                hid, wt + 524288, ffn_b2 + i * 256, xsb, nullptr);
        }
    }

    pool_k<<<BB * 16, 256, 0, stream>>>(xsb, part);
    final_k<<<BB, 256, 0, stream>>>(part, norm_g, norm_b, cls_w, cls_b, (float*)d_out);
}

// Round 16
// 681.815 us; speedup vs baseline: 1.0148x; 1.0148x over previous
//
#include <hip/hip_runtime.h>
#include <math.h>

// ---------------- model constants ----------------
#define BB 16
#define LL 2048
#define CHUNK 10
#define DD 256
#define NLAYERS 4
#define FFD 1024
#define NCLS 10
#define HSTRC 2056  // float2 stride per channel of Hf (2049 bins + pad)

typedef short bf16x8 __attribute__((ext_vector_type(8)));
typedef short s16x4 __attribute__((ext_vector_type(4)));
typedef float f32x4 __attribute__((ext_vector_type(4)));

__device__ __forceinline__ unsigned short f2bf(float f) {
    unsigned int u = __builtin_bit_cast(unsigned int, f);
    u = (u + 0x7FFF + ((u >> 16) & 1)) >> 16;
    return (unsigned short)u;
}
__device__ __forceinline__ float bf2f(unsigned short s) {
    unsigned int u = ((unsigned int)s) << 16;
    return __builtin_bit_cast(float, u);
}
__device__ __forceinline__ float bfLO(unsigned v) { return __builtin_bit_cast(float, v << 16); }
__device__ __forceinline__ float bfHI(unsigned v) { return __builtin_bit_cast(float, v & 0xFFFF0000u); }

#define PADC(a) ((a) + ((a) >> 4))

__device__ __forceinline__ float2 cmulf(float2 a, float2 b) {
    return make_float2(fmaf(-a.y, b.y, a.x * b.x), fmaf(a.y, b.x, a.x * b.y));
}

#define GLL16(gsrc, ldst) \
    __builtin_amdgcn_global_load_lds((const __attribute__((address_space(1))) void*)(gsrc), \
                                     (__attribute__((address_space(3))) void*)(ldst), 16, 0, 0)

// ================= embed: xs(bf16) = reshape(x)@inp_w + inp_b + PE =================
__global__ __launch_bounds__(256)
void embed_k(const float* __restrict__ x, const float* __restrict__ iw,
             const float* __restrict__ ib, unsigned short* __restrict__ xsb)
{
    const int tid = threadIdx.x;
    const size_t row0 = (size_t)blockIdx.x * 8;
    const int i2 = (tid >> 1) * 2;
    const float div = expf(-0.03597789207803197f * (float)i2);
    float wcol[CHUNK];
#pragma unroll
    for (int c = 0; c < CHUNK; ++c) wcol[c] = iw[c * DD + tid];
    const float bv = ib[tid];
    for (int rr = 0; rr < 8; ++rr) {
        size_t row = row0 + rr;
        int l = (int)(row & (LL - 1));
        const float* xr = x + row * CHUNK;
        float acc = bv;
#pragma unroll
        for (int c = 0; c < CHUNK; ++c) acc += xr[c] * wcol[c];
        float sv, cv;
        sincosf((float)l * div, &sv, &cv);
        acc += (tid & 1) ? cv : sv;
        xsb[row * DD + tid] = f2bf(acc);
    }
}

// ================= filter MLP (all layers): hTall[layer][d][l] =================
__global__ __launch_bounds__(256)
void filt_all_k(const float* __restrict__ fw1, const float* __restrict__ fb1,
                const float* __restrict__ fw2, const float* __restrict__ fb2,
                float* __restrict__ hTall)
{
    __shared__ float pe[16];
    __shared__ float hid[64];
    const int tid = threadIdx.x;
    const int layer = blockIdx.x >> 11;
    const int l = blockIdx.x & 2047;
    const float* w1 = fw1 + layer * 1024;
    const float* b1 = fb1 + layer * 64;
    const float* w2 = fw2 + layer * 16384;
    const float* b2 = fb2 + layer * 256;
    if (tid < 16) {
        int i2 = (tid >> 1) * 2;
        float div = expf(-0.5756462732485114f * (float)i2);
        float sv, cv;
        sincosf((float)l * div, &sv, &cv);
        pe[tid] = (tid & 1) ? cv : sv;
    }
    __syncthreads();
    if (tid < 64) {
        float a = b1[tid];
#pragma unroll
        for (int e = 0; e < 16; ++e) a += pe[e] * w1[e * 64 + tid];
        hid[tid] = 0.5f * a * (1.0f + erff(a * 0.70710678118f));
    }
    __syncthreads();
    float a = b2[tid];
#pragma unroll
    for (int h = 0; h < 64; ++h) a += hid[h] * w2[h * DD + tid];
    hTall[(size_t)layer * 524288 + (size_t)tid * LL + l] = a;
}

// ====== in-place radix-8 Stockham FFT, N=2048 = 8*8*8*4, single float2 buffer ======
__device__ __forceinline__ void dft4c(float2 a, float2 b, float2 c, float2 d,
                                      float2& F0, float2& F1, float2& F2, float2& F3)
{
    float t0r = a.x + c.x, t0i = a.y + c.y;
    float t1r = a.x - c.x, t1i = a.y - c.y;
    float t2r = b.x + d.x, t2i = b.y + d.y;
    float t3r = b.x - d.x, t3i = b.y - d.y;
    F0 = make_float2(t0r + t2r, t0i + t2i);
    F2 = make_float2(t0r - t2r, t0i - t2i);
    F1 = make_float2(t1r + t3i, t1i - t3r);   // t1 - i*t3
    F3 = make_float2(t1r - t3i, t1i + t3r);   // t1 + i*t3
}

template <int SH>
__device__ __forceinline__ void stage8ip(float2* __restrict__ A, int tid)
{
    constexpr int ST = 1 << SH;
    const int p = tid >> SH;
    const int q = tid & (ST - 1);
    float2 x0 = A[PADC(tid)];
    float2 x1 = A[PADC(tid + 256)];
    float2 x2 = A[PADC(tid + 512)];
    float2 x3 = A[PADC(tid + 768)];
    float2 x4 = A[PADC(tid + 1024)];
    float2 x5 = A[PADC(tid + 1280)];
    float2 x6 = A[PADC(tid + 1536)];
    float2 x7 = A[PADC(tid + 1792)];
    float2 E0, E1, E2, E3, O0, O1, O2, O3;
    dft4c(x0, x2, x4, x6, E0, E1, E2, E3);
    dft4c(x1, x3, x5, x7, O0, O1, O2, O3);
    const float C8 = 0.70710678118654752f;
    float2 y0 = make_float2(E0.x + O0.x, E0.y + O0.y);
    float2 y4 = make_float2(E0.x - O0.x, E0.y - O0.y);
    float a1 = C8 * (O1.x + O1.y), b1 = C8 * (O1.y - O1.x);       // w8^1 * O1
    float2 y1 = make_float2(E1.x + a1, E1.y + b1);
    float2 y5 = make_float2(E1.x - a1, E1.y - b1);
    float2 y2 = make_float2(E2.x + O2.y, E2.y - O2.x);            // -i * O2
    float2 y6 = make_float2(E2.x - O2.y, E2.y + O2.x);
    float a3 = -C8 * (O3.x - O3.y), b3 = -C8 * (O3.x + O3.y);     // w8^3 * O3
    float2 y3 = make_float2(E3.x + a3, E3.y + b3);
    float2 y7 = make_float2(E3.x - a3, E3.y - b3);
    const int k0 = p << SH;
    float s1, c1;
    __sincosf(-3.0679615757712823e-3f * (float)k0, &s1, &c1);     // -2pi/2048 * k0
    float2 w1 = make_float2(c1, s1);
    float2 w2 = cmulf(w1, w1);
    float2 w3 = cmulf(w2, w1);
    float2 w4 = cmulf(w2, w2);
    float2 w5 = cmulf(w3, w2);
    float2 w6 = cmulf(w3, w3);
    float2 w7 = cmulf(w4, w3);
    float2 o1 = cmulf(w1, y1);
    float2 o2 = cmulf(w2, y2);
    float2 o3 = cmulf(w3, y3);
    float2 o4 = cmulf(w4, y4);
    float2 o5 = cmulf(w5, y5);
    float2 o6 = cmulf(w6, y6);
    float2 o7 = cmulf(w7, y7);
    __syncthreads();
    const int ob = q + ((ST * p) << 3);
    A[PADC(ob)] = y0;
    A[PADC(ob + ST)] = o1;
    A[PADC(ob + 2 * ST)] = o2;
    A[PADC(ob + 3 * ST)] = o3;
    A[PADC(ob + 4 * ST)] = o4;
    A[PADC(ob + 5 * ST)] = o5;
    A[PADC(ob + 6 * ST)] = o6;
    A[PADC(ob + 7 * ST)] = o7;
    __syncthreads();
}

__device__ __forceinline__ void stage4fip(float2* __restrict__ A, int tid)
{
    float2 v[2][4];
#pragma unroll
    for (int jj = 0; jj < 2; ++jj) {
        int u = tid + (jj << 8);
        v[jj][0] = A[PADC(u)];
        v[jj][1] = A[PADC(u + 512)];
        v[jj][2] = A[PADC(u + 1024)];
        v[jj][3] = A[PADC(u + 1536)];
    }
    __syncthreads();
#pragma unroll
    for (int jj = 0; jj < 2; ++jj) {
        int u = tid + (jj << 8);
        float2 F0, F1, F2, F3;
        dft4c(v[jj][0], v[jj][1], v[jj][2], v[jj][3], F0, F1, F2, F3);
        A[PADC(u)] = F0;
        A[PADC(u + 512)] = F1;
        A[PADC(u + 1024)] = F2;
        A[PADC(u + 1536)] = F3;
    }
    __syncthreads();
}

__device__ __forceinline__ void fft2048ip(float2* __restrict__ A, int tid)
{
    stage8ip<0>(A, tid);
    stage8ip<3>(A, tid);
    stage8ip<6>(A, tid);
    stage4fip(A, tid);
}

// ================= Hf (all layers) = rfft_4096(zero-pad(h)) per channel =================
__global__ __launch_bounds__(256)
void ffth_all_k(const float* __restrict__ hTall, float2* __restrict__ Hfall)
{
    __shared__ float2 A2[2176];
    const int tid = threadIdx.x;
    const int layer = blockIdx.x >> 8;
    const int d = blockIdx.x & 255;
    const float2* rowf = reinterpret_cast<const float2*>(hTall + (size_t)layer * 524288 + (size_t)d * LL);
#pragma unroll
    for (int j = 0; j < 4; ++j) {
        int u = tid + (j << 8);
        A2[PADC(u)] = rowf[u];
        A2[PADC(u + 1024)] = make_float2(0.0f, 0.0f);
    }
    __syncthreads();
    fft2048ip(A2, tid);
    float2* hf = Hfall + ((size_t)layer * 256 + d) * HSTRC;
#pragma unroll
    for (int j = 0; j < 4; ++j) {
        int k = 1 + tid + (j << 8);
        int m = 2048 - k;
        float2 zk = A2[PADC(k)], zm = A2[PADC(m)];
        float Er = 0.5f * (zk.x + zm.x), Ei = 0.5f * (zk.y - zm.y);
        float Or = 0.5f * (zk.y + zm.y), Oi = -0.5f * (zk.x - zm.x);
        float ts, tc;
        __sincosf(-1.5339807878856412e-3f * (float)k, &ts, &tc);
        float TOr = tc * Or - ts * Oi, TOi = tc * Oi + ts * Or;
        hf[k] = make_float2(Er + TOr, Ei + TOi);
        hf[m] = make_float2(Er - TOr, -(Ei - TOi));
    }
    if (tid == 0) {
        float2 z0 = A2[PADC(0)];
        hf[0] = make_float2(z0.x + z0.y, z0.x - z0.y);
    }
}

// ====== fused conv3 + fft conv (single-buffer in-place): x0T(bf16) -> yT(bf16) ======
__global__ __launch_bounds__(256, 4)
void fftconv_k(const unsigned short* __restrict__ x0T, unsigned short* __restrict__ yT,
               const float2* __restrict__ Hf, const float* __restrict__ sw,
               const float* __restrict__ sb)
{
    __shared__ float2 A2[2176];
    const int tid = threadIdx.x;
    // XCD-locality swizzle: XCD c handles channels d in [32c, 32c+32), all b
    const int w = blockIdx.x;
    const int c = w & 7, s = w >> 3;
    const int d = c * 32 + (s & 31);
    const int b = s >> 5;
    const int blk = b * 256 + d;
    const float w0 = sw[d * 3], w1 = sw[d * 3 + 1], w2 = sw[d * 3 + 2];
    const float bv = sb[d];

    // ---- load bf16 row (field-swap permuted within 64-blocks) into LDS floats ----
    float* rawF = reinterpret_cast<float*>(A2);
    {
        const uint4* rowv = reinterpret_cast<const uint4*>(x0T + (size_t)blk * LL);
        uint4 ld = rowv[tid];
        int p = tid << 3;
        int lB = p & ~63;
        int p6 = p & 63;
        int fg = p6 >> 4;
        int m0 = (p6 >> 2) & 3;
        float4* d0 = reinterpret_cast<float4*>(rawF + lB + m0 * 16 + fg * 4);
        float4* d1 = reinterpret_cast<float4*>(rawF + lB + (m0 + 1) * 16 + fg * 4);
        *d0 = make_float4(bfLO(ld.x), bfHI(ld.x), bfLO(ld.y), bfHI(ld.y));
        *d1 = make_float4(bfLO(ld.z), bfHI(ld.z), bfLO(ld.w), bfHI(ld.w));
    }
    __syncthreads();
    // ---- depthwise conv3 + complex pack into regs ----
    float2 zv[4];
#pragma unroll
    for (int j = 0; j < 4; ++j) {
        int u = tid + (j << 8);
        float xm1 = (u == 0) ? 0.0f : rawF[2 * u - 1];
        float xc0 = rawF[2 * u];
        float xp1 = rawF[2 * u + 1];
        float xp2 = (u == 1023) ? 0.0f : rawF[2 * u + 2];
        zv[j].x = bv + w0 * xm1 + w1 * xc0 + w2 * xp1;
        zv[j].y = bv + w0 * xc0 + w1 * xp1 + w2 * xp2;
    }
    __syncthreads();
#pragma unroll
    for (int j = 0; j < 4; ++j) {
        int u = tid + (j << 8);
        A2[PADC(u)] = zv[j];
        A2[PADC(u + 1024)] = make_float2(0.0f, 0.0f);
    }
    __syncthreads();
    fft2048ip(A2, tid);
    // ---- untangle, multiply by H, retangle ----
    const float2* hf = Hf + (size_t)d * HSTRC;
#pragma unroll
    for (int j = 0; j < 4; ++j) {
        int k = 1 + tid + (j << 8);
        int m = 2048 - k;
        float2 zk = A2[PADC(k)], zm = A2[PADC(m)];
        float Er = 0.5f * (zk.x + zm.x), Ei = 0.5f * (zk.y - zm.y);
        float Or = 0.5f * (zk.y + zm.y), Oi = -0.5f * (zk.x - zm.x);
        float ts, tc;
        __sincosf(-1.5339807878856412e-3f * (float)k, &ts, &tc);
        float TOr = tc * Or - ts * Oi, TOi = tc * Oi + ts * Or;
        float Xpr = Er + TOr, Xpi = Ei + TOi;
        float Xmr = Er - TOr, Xmi = Ei - TOi;
        float2 hk = hf[k], hm = hf[m];
        float Ykr = Xpr * hk.x - Xpi * hk.y, Yki = Xpr * hk.y + Xpi * hk.x;
        float Cr = Xmr * hm.x + Xmi * hm.y, Ci = Xmi * hm.x - Xmr * hm.y;
        float Pr = 0.5f * (Ykr + Cr), Pi = 0.5f * (Yki + Ci);
        float Gr = 0.5f * (Ykr - Cr), Gi = 0.5f * (Yki - Ci);
        float Qr = tc * Gr + ts * Gi, Qi = tc * Gi - ts * Gr;
        A2[PADC(k)] = make_float2(Pr - Qi, -(Pi + Qr));
        A2[PADC(m)] = make_float2(Pr + Qi, Pi - Qr);
    }
    if (tid == 0) {
        float2 z0 = A2[PADC(0)];
        float2 h0 = hf[0];
        float X0 = z0.x + z0.y, X2 = z0.x - z0.y;
        float Y0 = X0 * h0.x, Y2 = X2 * h0.y;
        float P = 0.5f * (Y0 + Y2), Q = 0.5f * (Y0 - Y2);
        A2[PADC(0)] = make_float2(P, -Q);
    }
    __syncthreads();
    fft2048ip(A2, tid);
    const float sc = 1.0f / 2048.0f;
    unsigned* yrow = reinterpret_cast<unsigned*>(yT + (size_t)blk * LL);
#pragma unroll
    for (int j = 0; j < 4; ++j) {
        int u = tid + (j << 8);
        float2 v = A2[PADC(u)];
        float e = v.x * sc, o = -v.y * sc;
        yrow[u] = (unsigned)f2bf(e) | ((unsigned)f2bf(o) << 16);
    }
}

// ================= gate + transpose: yg(B,L,D) bf16 = yT * x1 * x2 =================
__global__ __launch_bounds__(256)
void gate_k(const unsigned short* __restrict__ yTb, const unsigned short* __restrict__ px,
            unsigned short* __restrict__ yg)
{
    __shared__ float t[64][65];
    const int tid = threadIdx.x;
    const int blk = blockIdx.x;
    const int b = blk >> 7;
    const int dt = (blk >> 5) & 3;
    const int lt = blk & 31;
    const int d0 = dt << 6, l0 = lt << 6;
    const int r0 = tid >> 6, c = tid & 63;
    for (int rr = 0; rr < 16; ++rr) {
        int dl = rr * 4 + r0;
        t[dl][c] = bf2f(yTb[(((size_t)(b << 8) + d0 + dl) << 11) + l0 + c]);
    }
    __syncthreads();
    const int lid = tid & 63, lr = tid >> 6;
    for (int k = 0; k < 16; ++k) {
        int ll = k * 4 + lr;
        int l = l0 + ll;
        size_t pb = ((size_t)(b * LL + l)) * 512;
        float v = t[lid][ll];
        float x1 = bf2f(px[pb + d0 + lid]);
        float x2 = bf2f(px[pb + 256 + d0 + lid]);
        yg[((size_t)(b * LL + l)) * DD + d0 + lid] = f2bf(v * x1 * x2);
    }
}

// ================= LN + cast to bf16 (bf16 xs input; only after embed) =================
__global__ __launch_bounds__(256)
void lncast_k(const unsigned short* __restrict__ xsb, const float* __restrict__ g,
              const float* __restrict__ b, unsigned short* __restrict__ o)
{
    const int tid = threadIdx.x, lane = tid & 63, wave = tid >> 6;
    const size_t row = (size_t)blockIdx.x * 4 + wave;
    s16x4 vv = reinterpret_cast<const s16x4*>(xsb + row * DD)[lane];
    float v0 = bf2f((unsigned short)vv[0]), v1 = bf2f((unsigned short)vv[1]);
    float v2 = bf2f((unsigned short)vv[2]), v3 = bf2f((unsigned short)vv[3]);
    float s = v0 + v1 + v2 + v3;
#pragma unroll
    for (int off = 32; off > 0; off >>= 1) s += __shfl_xor(s, off, 64);
    float mean = s * (1.0f / 256.0f);
    float e0 = v0 - mean, e1 = v1 - mean, e2 = v2 - mean, e3 = v3 - mean;
    float q = e0 * e0 + e1 * e1 + e2 * e2 + e3 * e3;
#pragma unroll
    for (int off = 32; off > 0; off >>= 1) q += __shfl_xor(q, off, 64);
    float rstd = rsqrtf(q * (1.0f / 256.0f) + 1e-5f);
    float4 gg = reinterpret_cast<const float4*>(g)[lane];
    float4 bb = reinterpret_cast<const float4*>(b)[lane];
    s16x4 r;
    r[0] = (short)f2bf(e0 * rstd * gg.x + bb.x);
    r[1] = (short)f2bf(e1 * rstd * gg.y + bb.y);
    r[2] = (short)f2bf(e2 * rstd * gg.z + bb.z);
    r[3] = (short)f2bf(e3 * rstd * gg.w + bb.w);
    *reinterpret_cast<s16x4*>(o + row * DD + lane * 4) = r;
}

// ================= weight cast + transpose, ALL matrices in one dispatch =================
__global__ __launch_bounds__(256)
void wcast_all_k(const float* __restrict__ in_proj_w, const float* __restrict__ out_w,
                 const float* __restrict__ ffn_w1, const float* __restrict__ ffn_w2,
                 unsigned short* __restrict__ WTb)
{
    const int bid = blockIdx.x;
    const int layer = bid / 768;
    const int r = bid % 768;
    const float* W; unsigned short* WT; int K, N, nt, kt;
    unsigned short* wt = WTb + (size_t)layer * 786432;
    if (r < 192)      { int i = r;       nt = i % 24; kt = i / 24; K = 256;  N = 768;
                        W = in_proj_w + (size_t)layer * 196608; WT = wt; }
    else if (r < 256) { int i = r - 192; nt = i % 8;  kt = i / 8;  K = 256;  N = 256;
                        W = out_w + (size_t)layer * 65536;      WT = wt + 196608; }
    else if (r < 512) { int i = r - 256; nt = i % 32; kt = i / 32; K = 256;  N = 1024;
                        W = ffn_w1 + (size_t)layer * 262144;    WT = wt + 262144; }
    else              { int i = r - 512; nt = i % 8;  kt = i / 8;  K = 1024; N = 256;
                        W = ffn_w2 + (size_t)layer * 262144;    WT = wt + 524288; }
    __shared__ float t[32][33];
    const int tx = threadIdx.x & 31, ty = threadIdx.x >> 5;
    const int n0 = nt * 32, k0 = kt * 32;
#pragma unroll
    for (int j = 0; j < 4; ++j)
        t[ty + 8 * j][tx] = W[(size_t)(k0 + ty + 8 * j) * N + n0 + tx];
    __syncthreads();
#pragma unroll
    for (int j = 0; j < 4; ++j)
        WT[(size_t)(n0 + ty + 8 * j) * K + k0 + tx] = f2bf(t[tx][ty + 8 * j]);
}

// ================= bf16 MFMA GEMM (generic) =================
// MODE 1: GELU -> bf16. MODE 2: += into bf16 out (RMW). MODE 3: x0 transposed + x1x2.
template <int K, int N, int MODE>
__global__ __launch_bounds__(256)
void gemm_k(const unsigned short* __restrict__ A, const unsigned short* __restrict__ WT,
            const float* __restrict__ bias, void* __restrict__ outp, void* __restrict__ outp2)
{
    constexpr int C = N / 128;
    __shared__ unsigned short ldsA[8192];
    __shared__ unsigned short ldsB[8192];
    const int tid = threadIdx.x;
    const int lane = tid & 63, wid = tid >> 6;
    const int nwg = gridDim.x;
    const int w = blockIdx.x;
    const int logical = (w & 7) * (nwg >> 3) + (w >> 3);
    const int row0 = (logical / C) * 128;
    const int col0 = (logical % C) * 128;
    const int wm = (wid >> 1) * 64, wn = (wid & 1) * 64;
    const int fr = lane & 15, fg = lane >> 4;

    f32x4 acc[4][4];
#pragma unroll
    for (int n = 0; n < 4; ++n) {
        float bv = bias[col0 + wn + n * 16 + fr];
#pragma unroll
        for (int m = 0; m < 4; ++m) {
            acc[m][n][0] = bv; acc[m][n][1] = bv; acc[m][n][2] = bv; acc[m][n][3] = bv;
        }
    }

    const int srow = wid * 8 + (lane >> 3);
    const int sc = lane & 7;

    for (int kt = 0; kt < K / 64; ++kt) {
        const int k0 = kt * 64;
#pragma unroll
        for (int it = 0; it < 4; ++it) {
            int row = it * 32 + srow;
            int cs = sc ^ (row & 7);
            const char* ga = (const char*)(A + (size_t)(row0 + row) * K + k0) + cs * 16;
            const char* gb = (const char*)(WT + (size_t)(col0 + row) * K + k0) + cs * 16;
            GLL16(ga, (char*)ldsA + it * 4096 + wid * 1024);
            GLL16(gb, (char*)ldsB + it * 4096 + wid * 1024);
        }
        __syncthreads();
#pragma unroll
        for (int ks = 0; ks < 2; ++ks) {
            bf16x8 af[4], bf[4];
#pragma unroll
            for (int m = 0; m < 4; ++m) {
                int ar = wm + m * 16 + fr;
                int slot = (ks * 4 + fg) ^ (ar & 7);
                af[m] = *reinterpret_cast<const bf16x8*>(ldsA + ar * 64 + slot * 8);
            }
#pragma unroll
            for (int n = 0; n < 4; ++n) {
                int br = wn + n * 16 + fr;
                int slot = (ks * 4 + fg) ^ (br & 7);
                bf[n] = *reinterpret_cast<const bf16x8*>(ldsB + br * 64 + slot * 8);
            }
#pragma unroll
            for (int m = 0; m < 4; ++m)
#pragma unroll
                for (int n = 0; n < 4; ++n)
                    acc[m][n] = __builtin_amdgcn_mfma_f32_16x16x32_bf16(af[m], bf[n], acc[m][n], 0, 0, 0);
        }
        __syncthreads();
    }

    if constexpr (MODE == 3) {
        if (col0 < 256) {
            const int b = row0 >> 11;
            const int lb0 = (row0 & (LL - 1)) + wm;
#pragma unroll
            for (int n = 0; n < 4; ++n) {
                int dcol = col0 + wn + n * 16 + fr;
                unsigned short* dst = (unsigned short*)outp +
                    (((size_t)(b << 8) + dcol) << 11) + lb0 + fg * 16;
                unsigned pk[8];
#pragma unroll
                for (int q = 0; q < 8; ++q) {
                    int m = q >> 1, r0 = (q & 1) * 2;
                    pk[q] = (unsigned)f2bf(acc[m][n][r0]) | ((unsigned)f2bf(acc[m][n][r0 + 1]) << 16);
                }
                *reinterpret_cast<uint4*>(dst)     = make_uint4(pk[0], pk[1], pk[2], pk[3]);
                *reinterpret_cast<uint4*>(dst + 8) = make_uint4(pk[4], pk[5], pk[6], pk[7]);
            }
        } else {
            unsigned short* px = (unsigned short*)outp2;
#pragma unroll
            for (int m = 0; m < 4; ++m) {
                int gr = row0 + wm + m * 16 + fg * 4;
#pragma unroll
                for (int n = 0; n < 4; ++n) {
                    int gc = col0 - 256 + wn + n * 16 + fr;
#pragma unroll
                    for (int r = 0; r < 4; ++r)
                        px[(size_t)(gr + r) * 512 + gc] = f2bf(acc[m][n][r]);
                }
            }
        }
        return;
    }

#pragma unroll
    for (int m = 0; m < 4; ++m) {
        int gr = row0 + wm + m * 16 + fg * 4;
#pragma unroll
        for (int n = 0; n < 4; ++n) {
            int gc = col0 + wn + n * 16 + fr;
#pragma unroll
            for (int r = 0; r < 4; ++r) {
                float v = acc[m][n][r];
                if constexpr (MODE == 1) v = 0.5f * v * (1.0f + erff(v * 0.70710678118f));
                if constexpr (MODE <= 1) {
                    ((unsigned short*)outp)[(size_t)(gr + r) * N + gc] = f2bf(v);
                } else {
                    unsigned short* o = (unsigned short*)outp + (size_t)(gr + r) * N + gc;
                    *o = f2bf(bf2f(*o) + v);
                }
            }
        }
    }
}

// ====== fused GEMM(N=256) + residual(bf16) + LayerNorm + bf16 cast ======
template <int K>
__global__ __launch_bounds__(256)
void gemm_ln_k(const unsigned short* __restrict__ A, const unsigned short* __restrict__ WT,
               const float* __restrict__ bias, const float* __restrict__ lng,
               const float* __restrict__ lnb, unsigned short* __restrict__ xsb,
               unsigned short* __restrict__ xln)
{
    __shared__ unsigned short ldsA[64 * 64];
    __shared__ unsigned short ldsB[256 * 64];
    const int tid = threadIdx.x;
    const int lane = tid & 63, wid = tid >> 6;
    const int nwg = gridDim.x;
    const int w = blockIdx.x;
    const int logical = (w & 7) * (nwg >> 3) + (w >> 3);
    const size_t row0 = (size_t)logical * 64;
    const int fr = lane & 15, fg = lane >> 4;

    f32x4 acc[16];
#pragma unroll
    for (int n = 0; n < 16; ++n) {
        float bv = bias[n * 16 + fr];
        acc[n][0] = bv; acc[n][1] = bv; acc[n][2] = bv; acc[n][3] = bv;
    }

    for (int kt = 0; kt < K / 64; ++kt) {
        const int k0 = kt * 64;
#pragma unroll
        for (int p = 0; p < 2; ++p) {
            int cch = p * 256 + tid;
            int row = cch >> 3;
            int cs = (cch & 7) ^ (row & 7);
            const char* ga = (const char*)(A + (row0 + row) * K + k0) + cs * 16;
            GLL16(ga, (char*)ldsA + p * 4096 + wid * 1024);
        }
#pragma unroll
        for (int p = 0; p < 8; ++p) {
            int cch = p * 256 + tid;
            int row = cch >> 3;
            int cs = (cch & 7) ^ (row & 7);
            const char* gb = (const char*)(WT + (size_t)row * K + k0) + cs * 16;
            GLL16(gb, (char*)ldsB + p * 4096 + wid * 1024);
        }
        __syncthreads();
#pragma unroll
        for (int ks = 0; ks < 2; ++ks) {
            int ar = wid * 16 + fr;
            int slotA = (ks * 4 + fg) ^ (ar & 7);
            bf16x8 af = *reinterpret_cast<const bf16x8*>(ldsA + ar * 64 + slotA * 8);
#pragma unroll
            for (int n = 0; n < 16; ++n) {
                int br = n * 16 + fr;
                int slotB = (ks * 4 + fg) ^ (br & 7);
                bf16x8 bf = *reinterpret_cast<const bf16x8*>(ldsB + br * 64 + slotB * 8);
                acc[n] = __builtin_amdgcn_mfma_f32_16x16x32_bf16(af, bf, acc[n], 0, 0, 0);
            }
        }
        __syncthreads();
    }

    const size_t rbase = row0 + wid * 16 + fg * 4;
#pragma unroll
    for (int r = 0; r < 4; ++r) {
        const unsigned short* xr = xsb + (rbase + r) * DD;
#pragma unroll
        for (int n = 0; n < 16; ++n)
            acc[n][r] += bf2f(xr[fr + 16 * n]);
    }
    float sm[4], sq[4];
#pragma unroll
    for (int r = 0; r < 4; ++r) {
        float s = 0.0f, q = 0.0f;
#pragma unroll
        for (int n = 0; n < 16; ++n) {
            float v = acc[n][r];
            s += v; q += v * v;
        }
#pragma unroll
        for (int off = 1; off < 16; off <<= 1) {
            s += __shfl_xor(s, off, 64);
            q += __shfl_xor(q, off, 64);
        }
        sm[r] = s * (1.0f / 256.0f);
        float var = q * (1.0f / 256.0f) - sm[r] * sm[r];
        sq[r] = rsqrtf(var + 1e-5f);
    }
    float gv[16], bvv[16];
#pragma unroll
    for (int n = 0; n < 16; ++n) {
        gv[n] = lng[fr + 16 * n];
        bvv[n] = lnb[fr + 16 * n];
    }
#pragma unroll
    for (int r = 0; r < 4; ++r) {
        unsigned short* xw = xsb + (rbase + r) * DD;
        unsigned short* lw = xln + (rbase + r) * DD;
#pragma unroll
        for (int n = 0; n < 16; ++n) {
            int gc = fr + 16 * n;
            float v = acc[n][r];
            xw[gc] = f2bf(v);
            lw[gc] = f2bf((v - sm[r]) * sq[r] * gv[n] + bvv[n]);
        }
    }
}

// ================= mean pool (partial), bf16 xs =================
__global__ __launch_bounds__(256)
void pool_k(const unsigned short* __restrict__ xsb, float* __restrict__ part)
{
    const int tid = threadIdx.x;
    const int b = blockIdx.x >> 4, g = blockIdx.x & 15;
    size_t base = ((size_t)b * LL + g * 128) * DD + tid;
    float s = 0.0f;
    for (int l = 0; l < 128; ++l) s += bf2f(xsb[base + (size_t)l * DD]);
    part[(size_t)blockIdx.x * DD + tid] = s;
}

// ================= final =================
__global__ __launch_bounds__(256)
void final_k(const float* __restrict__ part, const float* __restrict__ ng,
             const float* __restrict__ nb, const float* __restrict__ cw,
             const float* __restrict__ cb, float* __restrict__ out)
{
    __shared__ float pl[256];
    __shared__ float red[4], red2[4];
    const int tid = threadIdx.x, b = blockIdx.x;
    float m = 0.0f;
    for (int g = 0; g < 16; ++g) m += part[((size_t)b * 16 + g) * DD + tid];
    m *= (1.0f / (float)LL);
    const int lane = tid & 63, wave = tid >> 6;
    float s = m;
#pragma unroll
    for (int off = 32; off > 0; off >>= 1) s += __shfl_xor(s, off, 64);
    if (lane == 0) red[wave] = s;
    __syncthreads();
    float mean = (red[0] + red[1] + red[2] + red[3]) * (1.0f / 256.0f);
    float dm = m - mean;
    float qv = dm * dm;
#pragma unroll
    for (int off = 32; off > 0; off >>= 1) qv += __shfl_xor(qv, off, 64);
    if (lane == 0) red2[wave] = qv;
    __syncthreads();
    float var = (red2[0] + red2[1] + red2[2] + red2[3]) * (1.0f / 256.0f);
    pl[tid] = dm * rsqrtf(var + 1e-5f) * ng[tid] + nb[tid];
    __syncthreads();
    if (tid < NCLS) {
        float a = cb[tid];
        for (int dd = 0; dd < 256; ++dd) a += pl[dd] * cw[dd * NCLS + tid];
        out[b * NCLS + tid] = a;
    }
}

// ================= launcher =================
extern "C" void kernel_launch(void* const* d_in, const int* in_sizes, int n_in,
                              void* d_out, int out_size, void* d_ws, size_t ws_size,
                              hipStream_t stream)
{
    (void)in_sizes; (void)n_in; (void)out_size; (void)ws_size;
    const float* x        = (const float*)d_in[0];
    const float* inp_w    = (const float*)d_in[1];
    const float* inp_b    = (const float*)d_in[2];
    const float* in_proj_w= (const float*)d_in[3];
    const float* in_proj_b= (const float*)d_in[4];
    const float* short_w  = (const float*)d_in[5];
    const float* short_b  = (const float*)d_in[6];
    const float* filt_w1  = (const float*)d_in[7];
    const float* filt_b1  = (const float*)d_in[8];
    const float* filt_w2  = (const float*)d_in[9];
    const float* filt_b2  = (const float*)d_in[10];
    const float* out_w    = (const float*)d_in[11];
    const float* out_b    = (const float*)d_in[12];
    const float* ln1_g    = (const float*)d_in[13];
    const float* ln1_b    = (const float*)d_in[14];
    const float* ln2_g    = (const float*)d_in[15];
    const float* ln2_b    = (const float*)d_in[16];
    const float* ffn_w1   = (const float*)d_in[17];
    const float* ffn_b1   = (const float*)d_in[18];
    const float* ffn_w2   = (const float*)d_in[19];
    const float* ffn_b2   = (const float*)d_in[20];
    const float* norm_g   = (const float*)d_in[21];
    const float* norm_b   = (const float*)d_in[22];
    const float* cls_w    = (const float*)d_in[23];
    const float* cls_b    = (const float*)d_in[24];

    float* ws = (float*)d_ws;
    unsigned short* xsb  = (unsigned short*)ws;                 // 16MB bf16 residual stream
    unsigned short* xln  = (unsigned short*)(ws + 4194304);     // 16MB bf16
    unsigned short* x0T  = (unsigned short*)(ws + 8388608);     // 16MB bf16 [B][D][L']
    unsigned short* yT   = (unsigned short*)(ws + 12582912);    // 16MB bf16 [B][D][L]
    unsigned short* projx= (unsigned short*)(ws + 16777216);    // 32MB bf16 (x1,x2)
    unsigned short* ygp  = x0T;                                 // reuse x0T after fftconv
    unsigned short* hid  = x0T;                                 // 64MB span (x0T..projx)
    float* hTall         = ws + 25165824;                       // 4 x 2MB
    float2* Hfall        = (float2*)(ws + 27262976);            // 4 x 256 x 2056 float2
    float* part          = ws + 31473664;
    unsigned short* WTb  = (unsigned short*)(ws + 31539200);    // 4 x 786432 bf16

    // ---- prologue: weights cast, embed, LN1(0), filters+Hf (x-independent) ----
    wcast_all_k<<<3072, 256, 0, stream>>>(in_proj_w, out_w, ffn_w1, ffn_w2, WTb);
    embed_k<<<4096, 256, 0, stream>>>(x, inp_w, inp_b, xsb);
    lncast_k<<<8192, 256, 0, stream>>>(xsb, ln1_g, ln1_b, xln);
    filt_all_k<<<NLAYERS * 2048, 256, 0, stream>>>(filt_w1, filt_b1, filt_w2, filt_b2, hTall);
    ffth_all_k<<<NLAYERS * 256, 256, 0, stream>>>(hTall, Hfall);

    for (int i = 0; i < NLAYERS; ++i) {
        unsigned short* wt = WTb + (size_t)i * 786432;
        float2* Hf = Hfall + (size_t)i * 256 * HSTRC;
        gemm_k<256, 768, 3><<<1536, 256, 0, stream>>>(
            xln, wt, in_proj_b + i * 768, x0T, projx);
        fftconv_k<<<4096, 256, 0, stream>>>(x0T, yT, Hf, short_w + i * 768, short_b + i * 256);
        gate_k<<<2048, 256, 0, stream>>>(yT, projx, ygp);
        // out-proj: xs += ygp @ ow + ob ; xln = LN2(xs)
        gemm_ln_k<256><<<512, 256, 0, stream>>>(
            ygp, wt + 196608, out_b + i * 256, ln2_g + i * 256, ln2_b + i * 256, xsb, xln);
        gemm_k<256, 1024, 1><<<2048, 256, 0, stream>>>(
            xln, wt + 262144, ffn_b1 + i * 1024, hid, nullptr);
        if (i < NLAYERS - 1) {
            gemm_ln_k<1024><<<512, 256, 0, stream>>>(
                hid, wt + 524288, ffn_b2 + i * 256,
                ln1_g + (i + 1) * 256, ln1_b + (i + 1) * 256, xsb, xln);
        } else {
            gemm_k<1024, 256, 2><<<512, 256, 0, stream>>>(
                hid, wt + 524288, ffn_b2 + i * 256, xsb, nullptr);
        }
    }

    pool_k<<<BB * 16, 256, 0, stream>>>(xsb, part);
    final_k<<<BB, 256, 0, stream>>>(part, norm_g, norm_b, cls_w, cls_b, (float*)d_out);
}